// Round 3
// baseline (99.436 us; speedup 1.0000x reference)
//
#include <hip/hip_runtime.h>
#include <hip/hip_bf16.h>

#define B_    128
#define CIN_  64
#define COUT_ 64
#define KT    576   // CIN * 9, reordered as k' = (p*3+q)*64 + c

typedef __attribute__((ext_vector_type(8))) short  short8;
typedef __attribute__((ext_vector_type(4))) float  f32x4;

__device__ __forceinline__ unsigned short f2bf(float f) {
  union { float f; unsigned int u; } v; v.f = f;
  return (unsigned short)((v.u + 0x7FFFu + ((v.u >> 16) & 1u)) >> 16);  // RNE
}

// ---------------------------------------------------------------------------
// Pre-pass: xC[b][hp][wp][c] bf16, hp/wp in [0,34), zero borders.
// xC[b][hp][wp][c] = x[b][c][hp-1][wp-1] (0 outside). c innermost -> 8
// consecutive c = 16 B = one dwordx4 A-fragment load in the main kernel.
// ---------------------------------------------------------------------------
__global__ __launch_bounds__(256) void xC_kernel(const float* __restrict__ x,
                                                 unsigned short* __restrict__ xC) {
  const int hp = blockIdx.x, b = blockIdx.y, t = threadIdx.x;
  unsigned short* dst = xC + (size_t)(b * 34 + hp) * (34 * 64);
  const uint4 z = make_uint4(0u, 0u, 0u, 0u);
  if (hp == 0 || hp == 33) {                 // zero border rows: 34*64*2 B
    for (int i = t; i < 272; i += 256) ((uint4*)dst)[i] = z;
    return;
  }
  __shared__ unsigned short tile[64][33];    // pitch 33: conflict-free transpose
  {
    const int c = t >> 2, w0 = (t & 3) * 8;
    const float* src = x + (size_t)(b * 64 + c) * 1024 + (hp - 1) * 32 + w0;
    const float4 u = ((const float4*)src)[0];
    const float4 v = ((const float4*)src)[1];
    tile[c][w0 + 0] = f2bf(u.x); tile[c][w0 + 1] = f2bf(u.y);
    tile[c][w0 + 2] = f2bf(u.z); tile[c][w0 + 3] = f2bf(u.w);
    tile[c][w0 + 4] = f2bf(v.x); tile[c][w0 + 5] = f2bf(v.y);
    tile[c][w0 + 6] = f2bf(v.z); tile[c][w0 + 7] = f2bf(v.w);
  }
  __syncthreads();
  {
    const int w = t >> 3, c8 = (t & 7) * 8;  // interior wp = w+1
    unsigned v[8];
#pragma unroll
    for (int j = 0; j < 8; ++j) v[j] = tile[c8 + j][w];
    uint4 pk;
    pk.x = v[0] | (v[1] << 16);
    pk.y = v[2] | (v[3] << 16);
    pk.z = v[4] | (v[5] << 16);
    pk.w = v[6] | (v[7] << 16);
    *(uint4*)(dst + (w + 1) * 64 + c8) = pk;
  }
  if (t < 16) ((uint4*)(dst + (t & 1) * 33 * 64))[t >> 1] = z;  // border cols
}

// ---------------------------------------------------------------------------
// Main: grid 2048 = 1024 (h,w) x 2 d-halves. Block: 256 thr (4 waves), wave wv
// owns b in [wv*32, wv*32+32). W half staged ONCE into LDS in k'-order
// (XOR-swizzled 16B slots); k-loop is barrier-free: A = 2 global dwordx4,
// B = 2 ds_read_b128, 4 MFMA per step.
// ---------------------------------------------------------------------------
__global__ __launch_bounds__(256, 4) void lc_main(const float* __restrict__ Wt,
                                                  const float* __restrict__ bias,
                                                  const unsigned short* __restrict__ xC,
                                                  float* __restrict__ out) {
  __shared__ unsigned short Wl[32 * KT];   // 36864 B, row pitch 1152 B
  __shared__ float blds[32];

  const int bid = (int)blockIdx.x;
  const int swz = (bid & 7) * 256 + (bid >> 3);   // XCD-contiguous ranges
  const int hw = swz >> 1, half = swz & 1;
  const int h = hw >> 5, w = hw & 31;
  const int t = threadIdx.x, lane = t & 63, wv = t >> 6;
  const int l15 = lane & 15, lg = lane >> 4;

  if (t < 32) blds[t] = bias[(half * 32 + t) * 1024 + hw];

  {  // stage W[d=0..31 of this half][576] natural-coalesced read, k'-scatter write
    const float* Wsrc = Wt + (size_t)hw * (64 * KT) + (size_t)half * (32 * KT);
#pragma unroll 2
    for (int it = 0; it < 18; ++it) {
      const int f = (it * 256 + t) * 4;              // flat elem in [0,18432)
      const int d = (((unsigned)(f >> 6)) * 7282u) >> 16;   // f/576
      int kn = f - d * 576;
      int c = ((unsigned)kn * 7282u) >> 16;          // kn/9
      int r = kn - c * 9;                            // r = p*3+q
      const float4 v4 = *(const float4*)(Wsrc + f);
      const float vv[4] = {v4.x, v4.y, v4.z, v4.w};
#pragma unroll
      for (int j = 0; j < 4; ++j) {
        const int kp = r * 64 + c;                   // k'
        const int slot = (kp >> 3) ^ (d & 7);        // XOR-swizzled 16B slot
        Wl[d * KT + slot * 8 + (kp & 7)] = f2bf(vv[j]);
        if (++r == 9) { r = 0; ++c; }
      }
    }
  }
  __syncthreads();

  const unsigned short* xb0 = xC + (size_t)(wv * 32 + l15) * (34 * 34 * 64);
  const unsigned short* xb1 = xb0 + (size_t)16 * (34 * 34 * 64);

  f32x4 acc[2][2];
#pragma unroll
  for (int bt = 0; bt < 2; ++bt)
#pragma unroll
    for (int dt = 0; dt < 2; ++dt) acc[bt][dt] = (f32x4){0.f, 0.f, 0.f, 0.f};

#pragma unroll
  for (int step = 0; step < 18; ++step) {
    const int pq = step >> 1, p = pq / 3, q = pq - p * 3;
    const int c0 = (step & 1) * 32;
    const int aoff = ((h + p) * 34 + (w + q)) * 64 + c0 + lg * 8;
    const short8 a0 = *(const short8*)(xb0 + aoff);
    const short8 a1 = *(const short8*)(xb1 + aoff);
    const int sbase = step * 4 + lg;                 // k'>>3 of this lane's slot
#pragma unroll
    for (int dt = 0; dt < 2; ++dt) {
      const int dl = dt * 16 + l15;
      const short8 bf = *(const short8*)&Wl[dl * KT + ((sbase ^ (dl & 7)) << 3)];
      acc[0][dt] = __builtin_amdgcn_mfma_f32_16x16x32_bf16(a0, bf, acc[0][dt], 0, 0, 0);
      acc[1][dt] = __builtin_amdgcn_mfma_f32_16x16x32_bf16(a1, bf, acc[1][dt], 0, 0, 0);
    }
  }

  // epilogue: D col = lane&15 (d), row = (lane>>4)*4 + i (b)
#pragma unroll
  for (int dt = 0; dt < 2; ++dt) {
    const int dg = half * 32 + dt * 16 + l15;
    const float bv = blds[dt * 16 + l15];
#pragma unroll
    for (int bt = 0; bt < 2; ++bt) {
#pragma unroll
      for (int i = 0; i < 4; ++i) {
        const int b = wv * 32 + bt * 16 + lg * 4 + i;
        out[(size_t)b * (COUT_ * 1024) + (size_t)dg * 1024 + hw] = acc[bt][dt][i] + bv;
      }
    }
  }
}

extern "C" void kernel_launch(void* const* d_in, const int* in_sizes, int n_in,
                              void* d_out, int out_size, void* d_ws, size_t ws_size,
                              hipStream_t stream) {
  const float* x    = (const float*)d_in[0];
  const float* wt   = (const float*)d_in[1];
  const float* bias = (const float*)d_in[2];
  float* out        = (float*)d_out;
  unsigned short* xC = (unsigned short*)d_ws;   // 128*34*34*64*2 B = 18.9 MB

  xC_kernel<<<dim3(34, 128), 256, 0, stream>>>(x, xC);
  lc_main<<<2048, 256, 0, stream>>>(wt, bias, xC, out);
}

// Round 4
// 91.944 us; speedup vs baseline: 1.0815x; 1.0815x over previous
//
#include <hip/hip_runtime.h>
#include <hip/hip_bf16.h>

#define B_    128
#define CIN_  64
#define COUT_ 64
#define KT    576   // CIN * 9, reordered as k' = (p*3+q)*64 + c

typedef __attribute__((ext_vector_type(8))) short  short8;
typedef __attribute__((ext_vector_type(4))) float  f32x4;

__device__ __forceinline__ unsigned short f2bf(float f) {
  union { float f; unsigned int u; } v; v.f = f;
  return (unsigned short)((v.u + 0x7FFFu + ((v.u >> 16) & 1u)) >> 16);  // RNE
}

// ---------------------------------------------------------------------------
// Pre-pass: xC[b][hp][wp][c] bf16, hp/wp in [0,34), zero borders.
// xC[b][hp][wp][c] = x[b][c][hp-1][wp-1] (0 outside). c innermost -> 8
// consecutive c = 16 B = one dwordx4 A-fragment load in the main kernel.
// ---------------------------------------------------------------------------
__global__ __launch_bounds__(256) void xC_kernel(const float* __restrict__ x,
                                                 unsigned short* __restrict__ xC) {
  const int hp = blockIdx.x, b = blockIdx.y, t = threadIdx.x;
  unsigned short* dst = xC + (size_t)(b * 34 + hp) * (34 * 64);
  const uint4 z = make_uint4(0u, 0u, 0u, 0u);
  if (hp == 0 || hp == 33) {                 // zero border rows: 34*64*2 B
    for (int i = t; i < 272; i += 256) ((uint4*)dst)[i] = z;
    return;
  }
  __shared__ unsigned short tile[64][33];    // pitch 33: conflict-free transpose
  {
    const int c = t >> 2, w0 = (t & 3) * 8;
    const float* src = x + (size_t)(b * 64 + c) * 1024 + (hp - 1) * 32 + w0;
    const float4 u = ((const float4*)src)[0];
    const float4 v = ((const float4*)src)[1];
    tile[c][w0 + 0] = f2bf(u.x); tile[c][w0 + 1] = f2bf(u.y);
    tile[c][w0 + 2] = f2bf(u.z); tile[c][w0 + 3] = f2bf(u.w);
    tile[c][w0 + 4] = f2bf(v.x); tile[c][w0 + 5] = f2bf(v.y);
    tile[c][w0 + 6] = f2bf(v.z); tile[c][w0 + 7] = f2bf(v.w);
  }
  __syncthreads();
  {
    const int w = t >> 3, c8 = (t & 7) * 8;  // interior wp = w+1
    unsigned v[8];
#pragma unroll
    for (int j = 0; j < 8; ++j) v[j] = tile[c8 + j][w];
    uint4 pk;
    pk.x = v[0] | (v[1] << 16);
    pk.y = v[2] | (v[3] << 16);
    pk.z = v[4] | (v[5] << 16);
    pk.w = v[6] | (v[7] << 16);
    *(uint4*)(dst + (w + 1) * 64 + c8) = pk;
  }
  if (t < 16) ((uint4*)(dst + (t & 1) * 33 * 64))[t >> 1] = z;  // border cols
}

// ---------------------------------------------------------------------------
// Main: grid 2048 = 1024 (h,w) x 2 d-halves. 4 waves; wave wv owns b-range
// [wv*32, wv*32+32). W staged once: issue ALL 18 dwordx4 first (deep in-flight
// queue), then convert+scatter to k'-ordered XOR-swizzled LDS. Barrier-free
// k-loop in 3 groups of 6 steps with batched A-load bursts.
// ---------------------------------------------------------------------------
__global__ __launch_bounds__(256, 3) void lc_main(const float* __restrict__ Wt,
                                                  const float* __restrict__ bias,
                                                  const unsigned short* __restrict__ xC,
                                                  float* __restrict__ out) {
  __shared__ unsigned short Wl[32 * KT];   // 36864 B
  __shared__ float blds[32];

  const int bid = (int)blockIdx.x;
  const int swz = (bid & 7) * 256 + (bid >> 3);   // XCD-contiguous ranges
  const int hw = swz >> 1, half = swz & 1;
  const int h = hw >> 5, w = hw & 31;
  const int t = threadIdx.x, lane = t & 63, wv = t >> 6;
  const int l15 = lane & 15, lg = lane >> 4;

  if (t < 32) blds[t] = bias[(half * 32 + t) * 1024 + hw];

  // ---- W staging: phase 1 = issue all loads (no deps), phase 2 = scatter ----
  const float* Wsrc = Wt + (size_t)hw * (64 * KT) + (size_t)half * (32 * KT);
  float4 wreg[18];
#pragma unroll
  for (int i = 0; i < 18; ++i)
    wreg[i] = ((const float4*)Wsrc)[i * 256 + t];

#pragma unroll
  for (int i = 0; i < 18; ++i) {
    const int f = (i * 256 + t) * 4;               // flat elem in [0,18432)
    const int d = (((unsigned)(f >> 6)) * 7282u) >> 16;   // f/576
    int kn = f - d * 576;
    int c = ((unsigned)kn * 7282u) >> 16;          // kn/9
    int r = kn - c * 9;                            // r = p*3+q
    const float vv[4] = {wreg[i].x, wreg[i].y, wreg[i].z, wreg[i].w};
#pragma unroll
    for (int j = 0; j < 4; ++j) {
      const int kp = r * 64 + c;                   // k'
      const int slot = (kp >> 3) ^ (d & 7);        // XOR-swizzled 16B slot
      Wl[d * KT + slot * 8 + (kp & 7)] = f2bf(vv[j]);
      if (++r == 9) { r = 0; ++c; }
    }
  }
  __syncthreads();

  const unsigned short* xb0 = xC + (size_t)(wv * 32 + l15) * (34 * 34 * 64);
  const unsigned short* xb1 = xb0 + (size_t)16 * (34 * 34 * 64);

  f32x4 acc[2][2];
#pragma unroll
  for (int bt = 0; bt < 2; ++bt)
#pragma unroll
    for (int dt = 0; dt < 2; ++dt) acc[bt][dt] = (f32x4){0.f, 0.f, 0.f, 0.f};

#pragma unroll
  for (int g = 0; g < 3; ++g) {
    // A-load burst: 12 independent dwordx4 in flight
    short8 A0[6], A1[6];
#pragma unroll
    for (int s = 0; s < 6; ++s) {
      const int step = g * 6 + s;
      const int pq = step >> 1, p = pq / 3, q = pq - p * 3;
      const int c0 = (step & 1) * 32;
      const int aoff = ((h + p) * 34 + (w + q)) * 64 + c0 + lg * 8;
      A0[s] = *(const short8*)(xb0 + aoff);
      A1[s] = *(const short8*)(xb1 + aoff);
    }
#pragma unroll
    for (int s = 0; s < 6; ++s) {
      const int step = g * 6 + s;
      const int sbase = step * 4 + lg;             // k'>>3 of this lane's slot
#pragma unroll
      for (int dt = 0; dt < 2; ++dt) {
        const int dl = dt * 16 + l15;
        const short8 bf = *(const short8*)&Wl[dl * KT + ((sbase ^ (dl & 7)) << 3)];
        acc[0][dt] = __builtin_amdgcn_mfma_f32_16x16x32_bf16(A0[s], bf, acc[0][dt], 0, 0, 0);
        acc[1][dt] = __builtin_amdgcn_mfma_f32_16x16x32_bf16(A1[s], bf, acc[1][dt], 0, 0, 0);
      }
    }
  }

  // epilogue: D col = lane&15 (d), row = (lane>>4)*4 + i (b)
#pragma unroll
  for (int dt = 0; dt < 2; ++dt) {
    const int dg = half * 32 + dt * 16 + l15;
    const float bv = blds[dt * 16 + l15];
#pragma unroll
    for (int bt = 0; bt < 2; ++bt) {
#pragma unroll
      for (int i = 0; i < 4; ++i) {
        const int b = wv * 32 + bt * 16 + lg * 4 + i;
        out[(size_t)b * (COUT_ * 1024) + (size_t)dg * 1024 + hw] = acc[bt][dt][i] + bv;
      }
    }
  }
}

extern "C" void kernel_launch(void* const* d_in, const int* in_sizes, int n_in,
                              void* d_out, int out_size, void* d_ws, size_t ws_size,
                              hipStream_t stream) {
  const float* x    = (const float*)d_in[0];
  const float* wt   = (const float*)d_in[1];
  const float* bias = (const float*)d_in[2];
  float* out        = (float*)d_out;
  unsigned short* xC = (unsigned short*)d_ws;   // 128*34*34*64*2 B = 18.9 MB

  xC_kernel<<<dim3(34, 128), 256, 0, stream>>>(x, xC);
  lc_main<<<2048, 256, 0, stream>>>(wt, bias, xC, out);
}

// Round 5
// 72.845 us; speedup vs baseline: 1.3650x; 1.2622x over previous
//
#include <hip/hip_runtime.h>
#include <hip/hip_bf16.h>

#define KT 576   // CIN*9, GEMM k-order k' = (p*3+q)*64 + c

typedef __attribute__((ext_vector_type(8))) short  short8;
typedef __attribute__((ext_vector_type(4))) float  f32x4;

__device__ __forceinline__ unsigned short f2bf(float f) {
  union { float f; unsigned int u; } v; v.f = f;
  return (unsigned short)((v.u + 0x7FFFu + ((v.u >> 16) & 1u)) >> 16);  // RNE
}

// ---------------------------------------------------------------------------
// Pre-pass: xC2 bf16, layout [hp 34][wp 34][bb 8][cs 8][bl 16][cl 8]
// (= padded x with 16b x 8c micro-blocks contiguous). An MFMA A-fragment read
// (lane l15 -> bl, lg -> cs) is then one fully-coalesced 1KB wave load.
// ---------------------------------------------------------------------------
__global__ __launch_bounds__(256) void xC2_kernel(const float* __restrict__ x,
                                                  unsigned short* __restrict__ xC2) {
  const int hp = blockIdx.x, bb = blockIdx.y, t = threadIdx.x;
  __shared__ unsigned short tile[32 * 1024];   // [w 32][cs 8][bl 16][cl 8]
  const bool interior = (hp >= 1 && hp <= 32);
  if (interior) {
#pragma unroll 4
    for (int i = 0; i < 32; ++i) {
      const int row = i * 32 + (t >> 3);       // = bl*64 + c
      const int bl = row >> 6, c = row & 63;
      const int k = t & 7;                     // 16B chunk within 128B w-row
      const float4 v = *(const float4*)(x + ((size_t)(bb * 16 + bl) * 64 + c) * 1024 +
                                        (hp - 1) * 32 + k * 4);
      const int base = (k * 4) * 1024 + (c >> 3) * 128 + bl * 8 + (c & 7);
      tile[base]        = f2bf(v.x);
      tile[base + 1024] = f2bf(v.y);
      tile[base + 2048] = f2bf(v.z);
      tile[base + 3072] = f2bf(v.w);
    }
  }
  __syncthreads();
  unsigned short* dst = xC2 + (size_t)hp * 278528 + (size_t)bb * 1024;
  const uint4 z = make_uint4(0u, 0u, 0u, 0u);
  for (int idx = t; idx < 34 * 128; idx += 256) {
    const int wp = idx >> 7, s = idx & 127;
    uint4 v = z;
    if (interior && wp >= 1 && wp <= 32) v = *(const uint4*)&tile[(wp - 1) * 1024 + s * 8];
    *(uint4*)(dst + (size_t)wp * 8192 + s * 8) = v;
  }
}

// ---------------------------------------------------------------------------
// Main: grid 2048 = 1024 (h,w) x 2 d-halves; 4 waves, wave wv owns b-range
// [wv*32, wv*32+32). W staged once into k'-ordered XOR-swizzled LDS.
// Barrier-free k-loop: per 3-step group, A-loads (coalesced 1KB dwordx4 from
// xC2) prefetched one group ahead; 2 ds_read_b128 + 4 MFMA per step.
// ---------------------------------------------------------------------------
__global__ __launch_bounds__(256, 4) void lc_main(const float* __restrict__ Wt,
                                                  const float* __restrict__ bias,
                                                  const unsigned short* __restrict__ xC2,
                                                  float* __restrict__ out,
                                                  float* __restrict__ tmp,
                                                  int useTmp) {
  __shared__ unsigned short Wl[32 * KT];   // 36864 B
  __shared__ float blds[32];

  const int bid = (int)blockIdx.x;
  const int swz = (bid & 7) * 256 + (bid >> 3);   // XCD-contiguous ranges
  const int hw = swz >> 1, half = swz & 1;
  const int h = hw >> 5, w = hw & 31;
  const int t = threadIdx.x, lane = t & 63, wv = t >> 6;
  const int l15 = lane & 15, lg = lane >> 4;

  if (t < 32) blds[t] = bias[(half * 32 + t) * 1024 + hw];

  // ---- W staging: coalesced natural-order read, k'-scatter to swizzled LDS
  const float* Wsrc = Wt + (size_t)hw * (64 * KT) + (size_t)half * (32 * KT);
  float4 wreg[18];
#pragma unroll
  for (int i = 0; i < 18; ++i)
    wreg[i] = ((const float4*)Wsrc)[i * 256 + t];
#pragma unroll
  for (int i = 0; i < 18; ++i) {
    const int f = (i * 256 + t) * 4;               // flat elem in [0,18432)
    const int d = (((unsigned)(f >> 6)) * 7282u) >> 16;   // f/576
    int kn = f - d * 576;
    int c = ((unsigned)kn * 7282u) >> 16;          // kn/9
    int r = kn - c * 9;                            // r = p*3+q
    const float vv[4] = {wreg[i].x, wreg[i].y, wreg[i].z, wreg[i].w};
#pragma unroll
    for (int j = 0; j < 4; ++j) {
      const int kp = r * 64 + c;                   // k'
      const int slot = (kp >> 3) ^ (d & 7);        // XOR-swizzled 16B slot
      Wl[d * KT + slot * 8 + (kp & 7)] = f2bf(vv[j]);
      if (++r == 9) { r = 0; ++c; }
    }
  }
  __syncthreads();

  // lane-constant part of the A address (shorts): bb=wv*2(+bt), cs=chalf*4+lg, bl=l15
  const unsigned short* xA = xC2 + (size_t)wv * 2048 + lg * 128 + l15 * 8;

  f32x4 acc[2][2];
#pragma unroll
  for (int bt = 0; bt < 2; ++bt)
#pragma unroll
    for (int dt = 0; dt < 2; ++dt) acc[bt][dt] = (f32x4){0.f, 0.f, 0.f, 0.f};

  const int x7 = l15 & 7;
  const int wrow0 = l15 * KT;
  const int wrow1 = (16 + l15) * KT;

  short8 A0[2][3], A1[2][3];
#pragma unroll
  for (int s = 0; s < 3; ++s) {                    // prologue: group 0
    const int pq = s >> 1, p = pq / 3, q = pq - p * 3;
    const size_t off = (size_t)(h + p) * 278528 + (size_t)(w + q) * 8192 + (s & 1) * 512;
    A0[0][s] = *(const short8*)(xA + off);
    A1[0][s] = *(const short8*)(xA + off + 1024);
  }
#pragma unroll
  for (int g = 0; g < 6; ++g) {
    const int cur = g & 1;
    if (g < 5) {                                   // prefetch group g+1
#pragma unroll
      for (int s = 0; s < 3; ++s) {
        const int step = (g + 1) * 3 + s;
        const int pq = step >> 1, p = pq / 3, q = pq - p * 3;
        const size_t off = (size_t)(h + p) * 278528 + (size_t)(w + q) * 8192 + (step & 1) * 512;
        A0[cur ^ 1][s] = *(const short8*)(xA + off);
        A1[cur ^ 1][s] = *(const short8*)(xA + off + 1024);
      }
    }
#pragma unroll
    for (int s = 0; s < 3; ++s) {                  // compute group g
      const int step = g * 3 + s;
      const int sb = step * 4 + lg;
      const short8 b0 = *(const short8*)&Wl[wrow0 + ((sb ^ x7) << 3)];
      const short8 b1 = *(const short8*)&Wl[wrow1 + ((sb ^ x7) << 3)];
      acc[0][0] = __builtin_amdgcn_mfma_f32_16x16x32_bf16(A0[cur][s], b0, acc[0][0], 0, 0, 0);
      acc[1][0] = __builtin_amdgcn_mfma_f32_16x16x32_bf16(A1[cur][s], b0, acc[1][0], 0, 0, 0);
      acc[0][1] = __builtin_amdgcn_mfma_f32_16x16x32_bf16(A0[cur][s], b1, acc[0][1], 0, 0, 0);
      acc[1][1] = __builtin_amdgcn_mfma_f32_16x16x32_bf16(A1[cur][s], b1, acc[1][1], 0, 0, 0);
    }
  }

  if (useTmp) {
    // coalesced: tmp[hw][half][dl 32][b 128], full 64B-line stores
    float* tb = tmp + (size_t)(hw * 2 + half) * (32 * 128) + wv * 32;
#pragma unroll
    for (int dt = 0; dt < 2; ++dt) {
      const float bv = blds[dt * 16 + l15];
#pragma unroll
      for (int bt = 0; bt < 2; ++bt) {
        f32x4 v = acc[bt][dt];
        v[0] += bv; v[1] += bv; v[2] += bv; v[3] += bv;
        *(f32x4*)(tb + (dt * 16 + l15) * 128 + bt * 16 + lg * 4) = v;
      }
    }
  } else {
    // fallback: scattered direct stores (D col = lane&15 (d), row = lg*4+i (b))
#pragma unroll
    for (int dt = 0; dt < 2; ++dt) {
      const int dg = half * 32 + dt * 16 + l15;
      const float bv = blds[dt * 16 + l15];
#pragma unroll
      for (int bt = 0; bt < 2; ++bt) {
#pragma unroll
        for (int i = 0; i < 4; ++i) {
          const int b = wv * 32 + bt * 16 + lg * 4 + i;
          out[(size_t)b * 65536 + (size_t)dg * 1024 + hw] = acc[bt][dt][i] + bv;
        }
      }
    }
  }
}

// ---------------------------------------------------------------------------
// tmp[hw][half][dl][b] -> out[b][d][hw], both sides coalesced via LDS tile.
// ---------------------------------------------------------------------------
__global__ __launch_bounds__(256) void tr_out(const float* __restrict__ tmp,
                                              float* __restrict__ out) {
  const int h = blockIdx.x;        // 0..31
  const int d = blockIdx.y;        // 0..63
  const int half = d >> 5, dl = d & 31;
  const int t = threadIdx.x;
  __shared__ float ls[32 * 132];   // [w][b+pad4]
  {
    const int w = t >> 3, bc = t & 7;
    const float* src = tmp + ((size_t)((h * 32 + w) * 2 + half) * 32 + dl) * 128 + bc * 16;
    float* dst = ls + w * 132 + bc * 16;
#pragma unroll
    for (int k = 0; k < 4; ++k) ((float4*)dst)[k] = ((const float4*)src)[k];
  }
  __syncthreads();
  {
    const int b = t >> 1, wh = t & 1;
    float4 o[4];
#pragma unroll
    for (int k = 0; k < 4; ++k)
#pragma unroll
      for (int j = 0; j < 4; ++j)
        ((float*)&o[k])[j] = ls[(wh * 16 + k * 4 + j) * 132 + b];
    float* dst = out + (size_t)b * 65536 + (size_t)d * 1024 + h * 32 + wh * 16;
#pragma unroll
    for (int k = 0; k < 4; ++k) ((float4*)dst)[k] = o[k];
  }
}

extern "C" void kernel_launch(void* const* d_in, const int* in_sizes, int n_in,
                              void* d_out, int out_size, void* d_ws, size_t ws_size,
                              hipStream_t stream) {
  const float* x    = (const float*)d_in[0];
  const float* wt   = (const float*)d_in[1];
  const float* bias = (const float*)d_in[2];
  float* out        = (float*)d_out;

  unsigned short* xC2 = (unsigned short*)d_ws;          // 18,939,904 B
  const size_t XC2_BYTES = 18939904u;
  const size_t TMP_BYTES = 33554432u;                   // 1024*2*32*128*4
  const int useTmp = (ws_size >= XC2_BYTES + TMP_BYTES) ? 1 : 0;
  float* tmp = (float*)((char*)d_ws + XC2_BYTES);

  xC2_kernel<<<dim3(34, 8), 256, 0, stream>>>(x, xC2);
  lc_main<<<2048, 256, 0, stream>>>(wt, bias, xC2, out, tmp, useTmp);
  if (useTmp) tr_out<<<dim3(32, 64), 256, 0, stream>>>(tmp, out);
}